// Round 9
// baseline (22531.482 us; speedup 1.0000x reference)
//
#include <hip/hip_runtime.h>
#include <hip/hip_bf16.h>
#include <math.h>

#define BATCH 256
#define T_IN 256
#define T_OUT 32
#define E_DIM 512
#define H_DIM 1024
#define Y_DIM 1024
#define G_DIM 3072

typedef __attribute__((ext_vector_type(8))) __bf16 bf16x8;
typedef __attribute__((ext_vector_type(4))) float f32x4;
typedef __attribute__((ext_vector_type(4))) unsigned int u32x4;

__device__ __forceinline__ unsigned short f2bf_raw(float x) {
    unsigned int u = __builtin_bit_cast(unsigned int, x);
    u += 0x7FFFu + ((u >> 16) & 1u);
    return (unsigned short)(u >> 16);
}
__device__ __forceinline__ float bf2f(short s) {
    unsigned int u = ((unsigned int)(unsigned short)s) << 16;
    return __builtin_bit_cast(float, u);
}
__device__ __forceinline__ f32x4 mfma16(bf16x8 a, bf16x8 b, f32x4 c) {
    return __builtin_amdgcn_mfma_f32_16x16x32_bf16(a, b, c, 0, 0, 0);
}
__device__ __forceinline__ bf16x8 ldsb8(const short* p) {
    return __builtin_bit_cast(bf16x8, *(const u32x4*)p);
}
__device__ __forceinline__ bf16x8 loadg8(const short* p) {
    return __builtin_bit_cast(bf16x8, *(const u32x4*)p);
}
__device__ __forceinline__ bf16x8 loadf8(const float* p) {
    float4 f0 = *(const float4*)p;
    float4 f1 = *(const float4*)(p + 4);
    u32x4 v;
    v.x = ((unsigned)f2bf_raw(f0.y) << 16) | f2bf_raw(f0.x);
    v.y = ((unsigned)f2bf_raw(f0.w) << 16) | f2bf_raw(f0.z);
    v.z = ((unsigned)f2bf_raw(f1.y) << 16) | f2bf_raw(f1.x);
    v.w = ((unsigned)f2bf_raw(f1.w) << 16) | f2bf_raw(f1.z);
    return __builtin_bit_cast(bf16x8, v);
}

__global__ __launch_bounds__(256) void f32_to_bf16(
    const float* __restrict__ src, short* __restrict__ dst, int n4)
{
    for (int i = blockIdx.x * 256 + threadIdx.x; i < n4; i += gridDim.x * 256) {
        float4 f = *(const float4*)(src + 4 * (size_t)i);
        short4 o;
        o.x = (short)f2bf_raw(f.x); o.y = (short)f2bf_raw(f.y);
        o.z = (short)f2bf_raw(f.z); o.w = (short)f2bf_raw(f.w);
        *(short4*)(dst + 4 * (size_t)i) = o;
    }
}

// ---------------------------------------------------------------------------
// Persistent wavefront GRU. 256 blocks, 4 roles x 64 col-blocks of 16 h-cols:
//   role 0: Wih0 (gi0, one phase ahead)   role 1: Whh0 (gh0 + fuse -> h0)
//   role 2: Wih1 (gi1, one phase ahead)   role 3: Whh1 (gh1 + fuse -> h1, copy)
// Each block preloads its 48-row weight slice into LDS ONCE (<=99KB static,
// immune to the grid-barrier cache fences). Per phase: A streamed directly
// global->reg (per-lane fragments), 3 ds_read + 12 MFMA per K-step per wave,
// NO intra-step barriers. Grid barrier = R6-proven monotone counter.
// Phase schedule (T = seq len): r0 t=p [0,T-1]; r1 t=p-1 [1,T];
// r2 t=p-2 [2,T+1]; r3 t=p-3 [3,T+2]; phases = T+3.
// ---------------------------------------------------------------------------
__global__ __launch_bounds__(256) void persist2(
    int T, int dec,
    const float* __restrict__ emb, const int* __restrict__ xind,
    const float* __restrict__ yv,
    const short* __restrict__ W0i, const short* __restrict__ W0h,
    const float* __restrict__ b0i, const float* __restrict__ b0h,
    const short* __restrict__ W1i, const short* __restrict__ W1h,
    const float* __restrict__ b1i, const float* __restrict__ b1h,
    float* __restrict__ gi0, float* __restrict__ gi1,       // [2][B*G]
    float* __restrict__ h0f, short* __restrict__ h0b,       // [2][B*H]
    float* __restrict__ h1f, short* __restrict__ h1b,
    short* __restrict__ copydst,
    unsigned* __restrict__ bar)
{
    __shared__ short Wlds[49536];   // 48 x (1024+8) shorts = 99 KB (static; 160KB cap)

    const int bid = blockIdx.x;
    const int role = bid >> 6;          // 0..3
    const int cb = bid & 63;
    const int col0 = cb * 16;
    const int tid = threadIdx.x;
    const int lane = tid & 63;
    const int w = tid >> 6;
    const int lr = lane & 15, lk = lane >> 4;
    const int wbase = w * 64;           // wave's 64 rows

    const bool ih = !(role & 1);
    const int layer = role >> 1;
    const int Kx = ih ? (layer ? H_DIM : (dec ? Y_DIM : E_DIM)) : H_DIM;
    const int Kpad = Kx + 8;

    // ---- one-time W preload into LDS ----
    {
        const short* Wg = layer ? (ih ? W1i : W1h) : (ih ? W0i : W0h);
        const int nch = Kx >> 3;
        for (int i = tid; i < 48 * nch; i += 256) {
            int r = i / nch, c = i % nch;
            int g = r >> 4, cc = r & 15;
            const short* src = Wg + (size_t)(g * H_DIM + col0 + cc) * Kx + c * 8;
            *(u32x4*)&Wlds[r * Kpad + c * 8] = *(const u32x4*)src;
        }
    }
    // ---- bias preload (hh roles) ----
    float bi0v = 0.f, bi1v = 0.f, bi2v = 0.f, bh0v = 0.f, bh1v = 0.f, bh2v = 0.f;
    if (!ih) {
        const float* bi = layer ? b1i : b0i;
        const float* bh = layer ? b1h : b0h;
        int hc = col0 + lr;
        bi0v = bi[hc]; bi1v = bi[H_DIM + hc]; bi2v = bi[2 * H_DIM + hc];
        bh0v = bh[hc]; bh1v = bh[H_DIM + hc]; bh2v = bh[2 * H_DIM + hc];
    }
    __syncthreads();

    const int phases = T + 3;
    const size_t BH = (size_t)BATCH * H_DIM;
    const size_t BG = (size_t)BATCH * G_DIM;

    for (int p = 0; p < phases; ++p) {
        // per-role step index + activity
        int t = p - (role == 0 ? 0 : (role == 1 ? 1 : (role == 2 ? 2 : 3)));
        bool active = (t >= 0) && (t < T);

        if (active) {
            f32x4 zf = {0.f, 0.f, 0.f, 0.f};
            f32x4 acc[4][3] = {{zf,zf,zf},{zf,zf,zf},{zf,zf,zf},{zf,zf,zf}};
            bool skip = false;

            // ---- resolve A row pointers (4 m-frags, per-lane) ----
            const short* ab[4]; const float* af[4];
            bool abf = true;
            if (role == 0) {
                if (dec) {
                    if (t == 0) skip = true;   // y_in = 0 -> gi = 0
                    else {
                        abf = false;
                        #pragma unroll
                        for (int mf = 0; mf < 4; ++mf) {
                            int row = wbase + mf * 16 + lr;
                            af[mf] = yv + ((size_t)row * T_OUT + (t - 1)) * Y_DIM + lk * 8;
                        }
                    }
                } else {
                    abf = false;
                    #pragma unroll
                    for (int mf = 0; mf < 4; ++mf) {
                        int row = wbase + mf * 16 + lr;
                        int ridx = xind[(size_t)row * T_IN + t];
                        af[mf] = emb + (size_t)ridx * E_DIM + lk * 8;
                    }
                }
            } else {
                const short* src;
                if (role == 1)      src = h0b + ((p - 1) & 1) * BH;  // h0(t-1)
                else if (role == 2) src = h0b + ((p - 1) & 1) * BH;  // h0(t) for gi1
                else                src = h1b + ((p - 1) & 1) * BH;  // h1(t-1)
                #pragma unroll
                for (int mf = 0; mf < 4; ++mf) {
                    int row = wbase + mf * 16 + lr;
                    ab[mf] = src + (size_t)row * H_DIM + lk * 8;
                }
            }

            // ---- GEMM [64 rows/wave x 48 gate-cols], K = Kx ----
            if (!skip) {
                if (abf) {
                    #pragma unroll 2
                    for (int k0 = 0; k0 < Kx; k0 += 32) {
                        bf16x8 a0 = loadg8(ab[0] + k0), a1 = loadg8(ab[1] + k0);
                        bf16x8 a2 = loadg8(ab[2] + k0), a3 = loadg8(ab[3] + k0);
                        #pragma unroll
                        for (int g = 0; g < 3; ++g) {
                            bf16x8 wf = ldsb8(&Wlds[(g * 16 + lr) * Kpad + k0 + lk * 8]);
                            acc[0][g] = mfma16(a0, wf, acc[0][g]);
                            acc[1][g] = mfma16(a1, wf, acc[1][g]);
                            acc[2][g] = mfma16(a2, wf, acc[2][g]);
                            acc[3][g] = mfma16(a3, wf, acc[3][g]);
                        }
                    }
                } else {
                    #pragma unroll 2
                    for (int k0 = 0; k0 < Kx; k0 += 32) {
                        bf16x8 a0 = loadf8(af[0] + k0), a1 = loadf8(af[1] + k0);
                        bf16x8 a2 = loadf8(af[2] + k0), a3 = loadf8(af[3] + k0);
                        #pragma unroll
                        for (int g = 0; g < 3; ++g) {
                            bf16x8 wf = ldsb8(&Wlds[(g * 16 + lr) * Kpad + k0 + lk * 8]);
                            acc[0][g] = mfma16(a0, wf, acc[0][g]);
                            acc[1][g] = mfma16(a1, wf, acc[1][g]);
                            acc[2][g] = mfma16(a2, wf, acc[2][g]);
                            acc[3][g] = mfma16(a3, wf, acc[3][g]);
                        }
                    }
                }
            }

            if (ih) {
                // ---- write gi (raw, no bias) into buffer [p&1] ----
                float* gi = (role == 0 ? gi0 : gi1) + (p & 1) * BG;
                #pragma unroll
                for (int mf = 0; mf < 4; ++mf) {
                    #pragma unroll
                    for (int q = 0; q < 4; ++q) {
                        int row = wbase + mf * 16 + lk * 4 + q;
                        float* gr = gi + (size_t)row * G_DIM + col0 + lr;
                        gr[0]            = acc[mf][0][q];
                        gr[H_DIM]        = acc[mf][1][q];
                        gr[2 * H_DIM]    = acc[mf][2][q];
                    }
                }
            } else {
                // ---- fuse: gh(acc) + gi(global) -> GRU -> h ----
                const float* gi = (role == 1 ? gi0 : gi1) + ((p - 1) & 1) * BG;
                const float* hpf = (role == 1 ? h0f : h1f) + ((p - 1) & 1) * BH;
                float* hof = (role == 1 ? h0f : h1f) + (p & 1) * BH;
                short* hob = (role == 1 ? h0b : h1b) + (p & 1) * BH;
                short* cp = (role == 3) ? (copydst + (size_t)t * BH) : nullptr;
                int hc = col0 + lr;
                #pragma unroll
                for (int mf = 0; mf < 4; ++mf) {
                    #pragma unroll
                    for (int q = 0; q < 4; ++q) {
                        int row = wbase + mf * 16 + lk * 4 + q;
                        const float* gr = gi + (size_t)row * G_DIM + hc;
                        float ir = gr[0] + bi0v, iz = gr[H_DIM] + bi1v, in_ = gr[2 * H_DIM] + bi2v;
                        float hr = acc[mf][0][q] + bh0v;
                        float hz = acc[mf][1][q] + bh1v;
                        float hn = acc[mf][2][q] + bh2v;
                        float r = 1.f / (1.f + expf(-(ir + hr)));
                        float z = 1.f / (1.f + expf(-(iz + hz)));
                        float n = tanhf(in_ + r * hn);
                        size_t oi = (size_t)row * H_DIM + hc;
                        float hv = hpf[oi];
                        float o = (1.f - z) * n + z * hv;
                        hof[oi] = o;
                        short ob = (short)f2bf_raw(o);
                        hob[oi] = ob;
                        if (cp) cp[oi] = ob;
                    }
                }
            }
        }

        // ---- grid barrier (monotone counter; R6-proven) ----
        __syncthreads();
        if (tid == 0) {
            __threadfence();
            __hip_atomic_fetch_add(bar, 1u, __ATOMIC_RELEASE, __HIP_MEMORY_SCOPE_AGENT);
            const unsigned tgt = (unsigned)(p + 1) * 256u;
            while (__hip_atomic_load(bar, __ATOMIC_ACQUIRE, __HIP_MEMORY_SCOPE_AGENT) < tgt)
                __builtin_amdgcn_s_sleep(8);
            __threadfence();
        }
        __syncthreads();
    }
}

// ---------------------------------------------------------------------------
// tail kernels (unchanged from R8, all proven absmax 0)
// ---------------------------------------------------------------------------
__global__ __launch_bounds__(256) void score_gemm(
    const short* __restrict__ h2all, const short* __restrict__ enc,
    float* __restrict__ S)
{
    const int st = blockIdx.x;
    const int b = blockIdx.y;
    __shared__ __align__(16) short Hs[32 * 40];
    __shared__ __align__(16) short Es[64 * 40];
    const int tid = threadIdx.x;
    const int ch = (tid & 3) * 8;
    const int hrow = (tid >> 2) & 31;
    const int erow = tid >> 2;
    const short* hsrc = h2all + ((size_t)hrow * BATCH + b) * H_DIM + ch;
    const short* esrc = enc + ((size_t)(st * 64 + erow) * BATCH + b) * H_DIM + ch;
    short* hdst = &Hs[hrow * 40 + ch];
    short* edst = &Es[erow * 40 + ch];
    const int lane = tid & 63, w = tid >> 6;
    const int lr = lane & 15, ko = (lane >> 4) * 8;
    f32x4 acc0 = {0.f, 0.f, 0.f, 0.f}, acc1 = acc0;
    for (int k0 = 0; k0 < H_DIM; k0 += 32) {
        if (tid < 128) *(u32x4*)hdst = *(const u32x4*)(hsrc + k0);
        *(u32x4*)edst = *(const u32x4*)(esrc + k0);
        __syncthreads();
        bf16x8 e = ldsb8(&Es[(w * 16 + lr) * 40 + ko]);
        bf16x8 h0v = ldsb8(&Hs[lr * 40 + ko]);
        bf16x8 h1v = ldsb8(&Hs[(16 + lr) * 40 + ko]);
        acc0 = mfma16(h0v, e, acc0);
        acc1 = mfma16(h1v, e, acc1);
        __syncthreads();
    }
    int s = st * 64 + w * 16 + lr;
    #pragma unroll
    for (int q = 0; q < 4; ++q) {
        int t0 = (lane >> 4) * 4 + q;
        S[(size_t)b * 8192 + (size_t)t0 * 256 + s] = acc0[q];
        S[(size_t)b * 8192 + (size_t)(t0 + 16) * 256 + s] = acc1[q];
    }
}

__global__ __launch_bounds__(256) void softmax_all(float* __restrict__ S)
{
    size_t base = (size_t)blockIdx.x * 256;
    int t = threadIdx.x;
    float v = S[base + t];
    int lane = t & 63, w = t >> 6;
    float m = v;
    for (int off = 32; off; off >>= 1) m = fmaxf(m, __shfl_down(m, off));
    __shared__ float r1[4];
    if (!lane) r1[w] = m;
    __syncthreads();
    m = fmaxf(fmaxf(r1[0], r1[1]), fmaxf(r1[2], r1[3]));
    float ex = expf(v - m);
    float s = ex;
    for (int off = 32; off; off >>= 1) s += __shfl_down(s, off);
    __shared__ float r2[4];
    if (!lane) r2[w] = s;
    __syncthreads();
    s = r2[0] + r2[1] + r2[2] + r2[3];
    S[base + t] = ex / s;
}

__global__ __launch_bounds__(256) void attn_apply_all(
    const short* __restrict__ enc, const float* __restrict__ S,
    short* __restrict__ attn_bf)
{
    const int tc = blockIdx.x, b = blockIdx.y;
    __shared__ float al[8][256];
    const int tid = threadIdx.x;
    #pragma unroll
    for (int ti = 0; ti < 8; ++ti)
        al[ti][tid] = S[(size_t)b * 8192 + (size_t)(tc * 8 + ti) * 256 + tid];
    __syncthreads();
    float acc[8][4] = {};
    const short* eb = enc + (size_t)b * H_DIM + tid;
    for (int s = 0; s < 256; ++s) {
        const short* er = eb + (size_t)s * (BATCH * H_DIM);
        float e0 = bf2f(er[0]), e1 = bf2f(er[256]);
        float e2 = bf2f(er[512]), e3 = bf2f(er[768]);
        #pragma unroll
        for (int ti = 0; ti < 8; ++ti) {
            float av = al[ti][s];
            acc[ti][0] += av * e0; acc[ti][1] += av * e1;
            acc[ti][2] += av * e2; acc[ti][3] += av * e3;
        }
    }
    #pragma unroll
    for (int ti = 0; ti < 8; ++ti) {
        size_t m = (size_t)(tc * 8 + ti) * 256 + b;
        #pragma unroll
        for (int i = 0; i < 4; ++i)
            attn_bf[m * H_DIM + tid + i * 256] = (short)f2bf_raw(acc[ti][i]);
    }
}

__global__ __launch_bounds__(256) void map_gemm(
    const short* __restrict__ A1, const short* __restrict__ A2,
    const short* __restrict__ Wm, const float* __restrict__ bias,
    float* __restrict__ C)
{
    const int bm = blockIdx.x * 64, bn = blockIdx.y * 64;
    __shared__ __align__(16) short S1[64 * 40], S2[64 * 40], T1[64 * 40], T2[64 * 40];
    const int tid = threadIdx.x;
    const int r = tid >> 2, ch = (tid & 3) * 8;
    const short* a1 = A1 + (size_t)(bm + r) * 1024 + ch;
    const short* a2 = A2 + (size_t)(bm + r) * 1024 + ch;
    const short* w1 = Wm + (size_t)(bn + r) * 2048 + ch;
    const short* w2 = w1 + 1024;
    const int lane = tid & 63, w = tid >> 6;
    const int wm = (w >> 1) * 32, wn = (w & 1) * 32;
    const int lr = lane & 15, ko = (lane >> 4) * 8;
    f32x4 acc[2][2] = {{{0.f,0.f,0.f,0.f}}};
    for (int k0 = 0; k0 < 1024; k0 += 32) {
        *(u32x4*)&S1[r * 40 + ch] = *(const u32x4*)(a1 + k0);
        *(u32x4*)&S2[r * 40 + ch] = *(const u32x4*)(a2 + k0);
        *(u32x4*)&T1[r * 40 + ch] = *(const u32x4*)(w1 + k0);
        *(u32x4*)&T2[r * 40 + ch] = *(const u32x4*)(w2 + k0);
        __syncthreads();
        bf16x8 x1[2], x2[2], y1[2], y2[2];
        #pragma unroll
        for (int i = 0; i < 2; ++i) {
            x1[i] = ldsb8(&S1[(wm + i * 16 + lr) * 40 + ko]);
            x2[i] = ldsb8(&S2[(wm + i * 16 + lr) * 40 + ko]);
            y1[i] = ldsb8(&T1[(wn + i * 16 + lr) * 40 + ko]);
            y2[i] = ldsb8(&T2[(wn + i * 16 + lr) * 40 + ko]);
        }
        #pragma unroll
        for (int i = 0; i < 2; ++i) {
            #pragma unroll
            for (int jq = 0; jq < 2; ++jq) {
                acc[i][jq] = mfma16(x1[i], y1[jq], acc[i][jq]);
                acc[i][jq] = mfma16(x2[i], y2[jq], acc[i][jq]);
            }
        }
        __syncthreads();
    }
    #pragma unroll
    for (int i = 0; i < 2; ++i) {
        #pragma unroll
        for (int jq = 0; jq < 2; ++jq) {
            int col = bn + wn + jq * 16 + lr;
            float bv = bias[col];
            #pragma unroll
            for (int q = 0; q < 4; ++q) {
                int row = bm + wm + i * 16 + (lane >> 4) * 4 + q;
                C[(size_t)row * 1024 + col] = acc[i][jq][q] + bv;
            }
        }
    }
}

__global__ __launch_bounds__(256) void loss_all(
    const float* __restrict__ logits, const float* __restrict__ y,
    float* __restrict__ loss_acc)
{
    int m = blockIdx.x, t = threadIdx.x;
    int tt = m >> 8, b = m & 255;
    const float* lrow = logits + (size_t)m * Y_DIM;
    float l[4];
    #pragma unroll
    for (int i = 0; i < 4; ++i) l[i] = lrow[t + i * 256];
    float mx = fmaxf(fmaxf(l[0], l[1]), fmaxf(l[2], l[3]));
    int lane = t & 63, w = t >> 6;
    for (int off = 32; off; off >>= 1) mx = fmaxf(mx, __shfl_down(mx, off));
    __shared__ float sm[4];
    if (!lane) sm[w] = mx;
    __syncthreads();
    mx = fmaxf(fmaxf(sm[0], sm[1]), fmaxf(sm[2], sm[3]));
    float es = 0.f;
    #pragma unroll
    for (int i = 0; i < 4; ++i) es += expf(l[i] - mx);
    for (int off = 32; off; off >>= 1) es += __shfl_down(es, off);
    __shared__ float ss[4];
    if (!lane) ss[w] = es;
    __syncthreads();
    float sum = ss[0] + ss[1] + ss[2] + ss[3];
    float logZ = mx + logf(sum);
    const float* yrow = y + ((size_t)b * T_OUT + tt) * Y_DIM;
    float part = 0.f;
    #pragma unroll
    for (int i = 0; i < 4; ++i) part += yrow[t + i * 256] * (logZ - l[i]);
    for (int off = 32; off; off >>= 1) part += __shfl_down(part, off);
    __shared__ float sp[4];
    if (!lane) sp[w] = part;
    __syncthreads();
    if (t == 0) atomicAdd(loss_acc, sp[0] + sp[1] + sp[2] + sp[3]);
}

__global__ __launch_bounds__(256) void ysum_kernel(
    const float* __restrict__ y, float* __restrict__ ysum, int n)
{
    float s = 0.f;
    for (int i = blockIdx.x * 256 + threadIdx.x; i < n; i += gridDim.x * 256)
        s += y[i];
    int lane = threadIdx.x & 63, w = threadIdx.x >> 6;
    for (int off = 32; off; off >>= 1) s += __shfl_down(s, off);
    __shared__ float sw[4];
    if (!lane) sw[w] = s;
    __syncthreads();
    if (!threadIdx.x) atomicAdd(ysum, sw[0] + sw[1] + sw[2] + sw[3]);
}

__global__ __launch_bounds__(256) void init_kernel(
    float* __restrict__ h0f, float* __restrict__ h1f,
    short* __restrict__ h0b, short* __restrict__ h1b,
    float* __restrict__ loss, float* __restrict__ ysum,
    unsigned* __restrict__ bar)
{
    int i = blockIdx.x * 256 + threadIdx.x;   // 0..2*B*H-1 (both parity buffers)
    h0f[i] = 0.f; h1f[i] = 0.f; h0b[i] = 0; h1b[i] = 0;
    if (i == 0) { *loss = 0.f; *ysum = 0.f; bar[0] = 0u; bar[1] = 0u; }
}

__global__ void final_kernel(const float* __restrict__ loss,
                             const float* __restrict__ ysum,
                             float* __restrict__ out)
{
    if (threadIdx.x == 0) out[0] = loss[0] / ysum[0];
}

// ---------------------------------------------------------------------------
extern "C" void kernel_launch(void* const* d_in, const int* in_sizes, int n_in,
                              void* d_out, int out_size, void* d_ws, size_t ws_size,
                              hipStream_t stream)
{
    const int*   x     = (const int*)d_in[0];
    const float* y     = (const float*)d_in[1];
    const float* emb   = (const float*)d_in[2];
    const float* eWih0 = (const float*)d_in[3];
    const float* eWhh0 = (const float*)d_in[4];
    const float* ebih0 = (const float*)d_in[5];
    const float* ebhh0 = (const float*)d_in[6];
    const float* eWih1 = (const float*)d_in[7];
    const float* eWhh1 = (const float*)d_in[8];
    const float* ebih1 = (const float*)d_in[9];
    const float* ebhh1 = (const float*)d_in[10];
    const float* dWih0 = (const float*)d_in[11];
    const float* dWhh0 = (const float*)d_in[12];
    const float* dbih0 = (const float*)d_in[13];
    const float* dbhh0 = (const float*)d_in[14];
    const float* dWih1 = (const float*)d_in[15];
    const float* dWhh1 = (const float*)d_in[16];
    const float* dbih1 = (const float*)d_in[17];
    const float* dbhh1 = (const float*)d_in[18];
    const float* mapW  = (const float*)d_in[19];
    const float* mapb  = (const float*)d_in[20];
    float* out = (float*)d_out;

    // ---- workspace (~225 MB peak; aliases reuse dead regions) ----
    char* p = (char*)d_ws;
    auto take = [&](size_t n) { char* q = p; p += (n + 255) & ~(size_t)255; return q; };
    short* enc_bf = (short*)take((size_t)T_IN * BATCH * H_DIM * 2);   // 134 MB
    char* wslab = p;
    short* eWih0b = (short*)take((size_t)G_DIM * E_DIM * 2);
    short* eWhh0b = (short*)take((size_t)G_DIM * H_DIM * 2);
    short* eWih1b = (short*)take((size_t)G_DIM * H_DIM * 2);
    short* eWhh1b = (short*)take((size_t)G_DIM * H_DIM * 2);
    short* dWih0b = (short*)take((size_t)G_DIM * Y_DIM * 2);
    short* dWhh0b = (short*)take((size_t)G_DIM * H_DIM * 2);
    short* dWih1b = (short*)take((size_t)G_DIM * H_DIM * 2);
    short* dWhh1b = (short*)take((size_t)G_DIM * H_DIM * 2);
    short* mapWb  = (short*)take((size_t)Y_DIM * 2 * H_DIM * 2);
    float* gi0 = (float*)take((size_t)2 * BATCH * G_DIM * 4);   // 6.3 MB
    float* gi1 = (float*)take((size_t)2 * BATCH * G_DIM * 4);
    float* h0f = (float*)take((size_t)2 * BATCH * H_DIM * 4);
    float* h1f = (float*)take((size_t)2 * BATCH * H_DIM * 4);
    short* h0b = (short*)take((size_t)2 * BATCH * H_DIM * 2);
    short* h1b = (short*)take((size_t)2 * BATCH * H_DIM * 2);
    short* h2all = (short*)take((size_t)T_OUT * BATCH * H_DIM * 2);  // 16.8 MB
    float* loss_acc = (float*)take(256);
    float* ysum = loss_acc + 1;
    unsigned* bar = (unsigned*)(loss_acc + 8);
    // aliases onto dead regions:
    float* logits  = (float*)enc_bf;                     // enc dead at map time
    short* attn_bf = (short*)wslab;                      // over dead enc weights
    float* S       = (float*)(wslab + (size_t)20 * 1024 * 1024);

    dim3 blk(256);

    f32_to_bf16<<<dim3(512), blk, 0, stream>>>(eWih0, eWih0b, G_DIM * E_DIM / 4);
    f32_to_bf16<<<dim3(512), blk, 0, stream>>>(eWhh0, eWhh0b, G_DIM * H_DIM / 4);
    f32_to_bf16<<<dim3(512), blk, 0, stream>>>(eWih1, eWih1b, G_DIM * H_DIM / 4);
    f32_to_bf16<<<dim3(512), blk, 0, stream>>>(eWhh1, eWhh1b, G_DIM * H_DIM / 4);
    f32_to_bf16<<<dim3(512), blk, 0, stream>>>(dWih0, dWih0b, G_DIM * Y_DIM / 4);
    f32_to_bf16<<<dim3(512), blk, 0, stream>>>(dWhh0, dWhh0b, G_DIM * H_DIM / 4);
    f32_to_bf16<<<dim3(512), blk, 0, stream>>>(dWih1, dWih1b, G_DIM * H_DIM / 4);
    f32_to_bf16<<<dim3(512), blk, 0, stream>>>(dWhh1, dWhh1b, G_DIM * H_DIM / 4);
    f32_to_bf16<<<dim3(512), blk, 0, stream>>>(mapW, mapWb, Y_DIM * 2 * H_DIM / 4);

    init_kernel<<<dim3(2 * BATCH * H_DIM / 256), blk, 0, stream>>>(
        h0f, h1f, h0b, h1b, loss_acc, ysum, bar);
    ysum_kernel<<<dim3(2048), blk, 0, stream>>>(y, ysum, BATCH * T_OUT * Y_DIM);

    // -------- encoder: one persistent launch, T+3 = 259 phases --------
    persist2<<<dim3(256), blk, 0, stream>>>(
        T_IN, 0, emb, x, y,
        eWih0b, eWhh0b, ebih0, ebhh0,
        eWih1b, eWhh1b, ebih1, ebhh1,
        gi0, gi1, h0f, h0b, h1f, h1b,
        enc_bf, bar);

    // -------- decoder: one persistent launch, 35 phases --------
    persist2<<<dim3(256), blk, 0, stream>>>(
        T_OUT, 1, emb, x, y,
        dWih0b, dWhh0b, dbih0, dbhh0,
        dWih1b, dWhh1b, dbih1, dbhh1,
        gi0, gi1, h0f, h0b, h1f, h1b,
        h2all, bar + 1);

    // -------- batched attention + map + loss --------
    score_gemm<<<dim3(4, 256), blk, 0, stream>>>(h2all, enc_bf, S);
    softmax_all<<<dim3(8192), blk, 0, stream>>>(S);
    attn_apply_all<<<dim3(4, 256), blk, 0, stream>>>(enc_bf, S, attn_bf);
    map_gemm<<<dim3(128, 16), blk, 0, stream>>>(attn_bf, h2all, mapWb, mapb, logits);
    loss_all<<<dim3(8192), blk, 0, stream>>>(logits, y, loss_acc);

    final_kernel<<<dim3(1), dim3(64), 0, stream>>>(loss_acc, ysum, out);
}